// Round 1
// baseline (1797.824 us; speedup 1.0000x reference)
//
#include <hip/hip_runtime.h>
#include <math.h>

// Shapes (fixed): B=32, M=2, C=256, H=W=16, N=256, DIM=256, THR=0.1, RATIO=0.8
// out: fused (32,256,16,16) = 2,097,152 floats, then auto_enc_loss (1 float)

__device__ __forceinline__ unsigned mapf(float f) {
  unsigned u = __float_as_uint(f);
  return (u & 0x80000000u) ? ~u : (u | 0x80000000u);   // monotone float->uint
}
__device__ __forceinline__ float unmapf(unsigned u) {
  unsigned v = (u & 0x80000000u) ? (u & 0x7fffffffu) : ~u;
  return __uint_as_float(v);
}

__global__ void init_k(float* lacc, unsigned* mm) {
  lacc[0] = 0.f;
  mm[0] = 0xFFFFFFFFu;  // min accumulator (mapped)
  mm[1] = 0u;           // max accumulator (mapped)
}

// 3x3 SAME conv, 256 in-ch, 32 out-ch per block, 16x16 images.
// grid: (8, G). block: 256 = 16 oc-groups x 16 rows; thread does 2 oc x 16 px.
// LOSS: accumulate sum((acc - xref)^2) into lacc instead of writing out.
template<bool RELU, bool LOSS>
__global__ __launch_bounds__(256) void conv3x3_k(
    const float* __restrict__ in, const float* __restrict__ wgt,
    const float* __restrict__ bias, const float* __restrict__ xref,
    float* __restrict__ out, float* __restrict__ lacc)
{
  const int g   = blockIdx.y;
  const int oc0 = blockIdx.x * 32;
  const int t   = threadIdx.x;
  const int row = t & 15;    // output row
  const int ocg = t >> 4;    // 0..15, 2 oc each
  const int lpy = t >> 4, lpx = t & 15;  // pixel for staging loads

  __shared__ float s_in[8 * 360];  // 8 ch x 18 rows x stride 20 (zero halo persists)
  __shared__ float s_w[32 * 73];   // 32 oc x 72 (+1 pad -> bank spread)

  for (int i = t; i < 8 * 360; i += 256) s_in[i] = 0.f;

  float acc[2][16];
  const float b0 = bias[oc0 + ocg * 2 + 0];
  const float b1 = bias[oc0 + ocg * 2 + 1];
#pragma unroll
  for (int p = 0; p < 16; ++p) { acc[0][p] = b0; acc[1][p] = b1; }

  const float* inb = in + (size_t)g * 65536;

  for (int ic0 = 0; ic0 < 256; ic0 += 8) {
    __syncthreads();
#pragma unroll
    for (int i = 0; i < 8; ++i)
      s_in[i * 360 + (lpy + 1) * 20 + (lpx + 1)] = inb[(ic0 + i) * 256 + t];
    for (int idx = t; idx < 32 * 72; idx += 256) {
      int o = idx / 72, r = idx - o * 72;
      s_w[o * 73 + r] = wgt[(size_t)(oc0 + o) * 2304 + ic0 * 9 + r];
    }
    __syncthreads();
#pragma unroll
    for (int i = 0; i < 8; ++i) {
      const int wbase = (ocg * 2) * 73 + i * 9;
#pragma unroll
      for (int ky = 0; ky < 3; ++ky) {
        float rv[18];
        const int rbase = i * 360 + (row + ky) * 20;
#pragma unroll
        for (int c4 = 0; c4 < 4; ++c4) {
          float4 v = *(const float4*)&s_in[rbase + c4 * 4];
          rv[c4 * 4 + 0] = v.x; rv[c4 * 4 + 1] = v.y;
          rv[c4 * 4 + 2] = v.z; rv[c4 * 4 + 3] = v.w;
        }
        rv[16] = s_in[rbase + 16];
        rv[17] = s_in[rbase + 17];
#pragma unroll
        for (int o = 0; o < 2; ++o) {
          const float w0 = s_w[wbase + o * 73 + ky * 3 + 0];
          const float w1 = s_w[wbase + o * 73 + ky * 3 + 1];
          const float w2 = s_w[wbase + o * 73 + ky * 3 + 2];
#pragma unroll
          for (int p = 0; p < 16; ++p)
            acc[o][p] += w0 * rv[p] + w1 * rv[p + 1] + w2 * rv[p + 2];
        }
      }
    }
  }

  if (!LOSS) {
#pragma unroll
    for (int o = 0; o < 2; ++o) {
      float* op = out + (size_t)g * 65536 + (size_t)(oc0 + ocg * 2 + o) * 256 + row * 16;
#pragma unroll
      for (int p4 = 0; p4 < 4; ++p4) {
        float4 r;
        r.x = RELU ? fmaxf(acc[o][p4 * 4 + 0], 0.f) : acc[o][p4 * 4 + 0];
        r.y = RELU ? fmaxf(acc[o][p4 * 4 + 1], 0.f) : acc[o][p4 * 4 + 1];
        r.z = RELU ? fmaxf(acc[o][p4 * 4 + 2], 0.f) : acc[o][p4 * 4 + 2];
        r.w = RELU ? fmaxf(acc[o][p4 * 4 + 3], 0.f) : acc[o][p4 * 4 + 3];
        *(float4*)&op[p4 * 4] = r;
      }
    }
  } else {
    float ls = 0.f;
#pragma unroll
    for (int o = 0; o < 2; ++o) {
      const float* xp = xref + (size_t)g * 65536 + (size_t)(oc0 + ocg * 2 + o) * 256 + row * 16;
#pragma unroll
      for (int p = 0; p < 16; ++p) {
        float d = acc[o][p] - xp[p];
        ls += d * d;
      }
    }
#pragma unroll
    for (int off = 32; off; off >>= 1) ls += __shfl_down(ls, off);
    __shared__ float sred[4];
    const int wid = t >> 6, lane = t & 63;
    if (lane == 0) sred[wid] = ls;
    __syncthreads();
    if (t == 0) atomicAdd(lacc, sred[0] + sred[1] + sred[2] + sred[3]);
  }
}

// Per-batch slot maps: counts per modality (feat_v > 0.1), rank-budget adjust,
// dest slots. smr[b][d] = m*256+r (or -1), vd[b][d] = feat_v value (0 invalid).
__global__ __launch_bounds__(256) void slots_k(const float* __restrict__ fv,
                                               int* __restrict__ smr,
                                               float* __restrict__ vd)
{
  const int b = blockIdx.x, t = threadIdx.x;
  const float v0 = fv[(size_t)b * 512 + t];
  const float v1 = fv[(size_t)b * 512 + 256 + t];
  const unsigned long long bal0 = __ballot(v0 > 0.1f);
  const unsigned long long bal1 = __ballot(v1 > 0.1f);
  __shared__ int cnt0[4], cnt1[4], fc[2];
  const int wid = t >> 6, lane = t & 63;
  if (lane == 0) { cnt0[wid] = __popcll(bal0); cnt1[wid] = __popcll(bal1); }
  smr[b * 256 + t] = -1;
  vd[b * 256 + t] = 0.f;
  __syncthreads();
  if (t == 0) {
    int c0 = cnt0[0] + cnt0[1] + cnt0[2] + cnt0[3];
    int c1 = cnt1[0] + cnt1[1] + cnt1[2] + cnt1[3];
    int total = c0 + c1;
    int f0, f1;
    if (total > 256) {  // kmin = min(C,N) = 256
      // rintf = round-half-even, matches jnp.round; same f32 arithmetic as ref
      int a0 = (int)rintf(256.0f * (float)c0 / (float)total);
      f0 = a0; f1 = 256 - a0;  // adj[:, -1] = DIM - adj[:, 0]
    } else { f0 = c0; f1 = c1; }
    fc[0] = max(f0, 0); fc[1] = max(f1, 0);
  }
  __syncthreads();
  const int c0 = fc[0], c1 = fc[1];
  if (t < c0) { smr[b * 256 + t] = t; vd[b * 256 + t] = v0; }
  if (t < c1) {
    int d = c0 + t;
    if (d < 256) { smr[b * 256 + d] = 256 + t; vd[b * 256 + d] = v1; }
  }
}

// A[b][i][j] = (i valid ? fs[b,m_i,r_i,j] : 0) * vd[b][j]
// Bm[b][j][k] = (k valid ? fd[b,m_k,j,r_k] : 0)     (this is nd)
__global__ __launch_bounds__(256) void assemble_k(
    const float* __restrict__ fs, const float* __restrict__ fd,
    const int* __restrict__ smr, const float* __restrict__ vd,
    float* __restrict__ A, float* __restrict__ Bm)
{
  const int b = blockIdx.y;
  const int r0 = blockIdx.x * 16;
  const int t = threadIdx.x;
  const int scol = smr[b * 256 + t];
  const float vcol = vd[b * 256 + t];
  for (int ii = 0; ii < 16; ++ii) {
    const int i = r0 + ii;
    const int si = smr[b * 256 + i];
    float a = 0.f;
    if (si >= 0) {
      int m = si >> 8, r = si & 255;
      a = fs[(((size_t)b * 2 + m) * 256 + r) * 256 + t] * vcol;
    }
    A[((size_t)b * 256 + i) * 256 + t] = a;
    float nv = 0.f;
    if (scol >= 0) {
      int m = scol >> 8, r = scol & 255;
      nv = fd[(((size_t)b * 2 + m) * 256 + i) * 256 + r];
    }
    Bm[((size_t)b * 256 + i) * 256 + t] = nv;
  }
}

// rec[b] = A[b] @ Bm[b], 256x256x256 fp32. grid (16, 32), block 256 (16x16),
// 64x64 tiles, 4x4 per thread, kt=16.
__global__ __launch_bounds__(256) void gemm_k(const float* __restrict__ A,
                                              const float* __restrict__ Bm,
                                              float* __restrict__ Cm)
{
  const int b = blockIdx.y;
  const int i0 = (blockIdx.x >> 2) * 64, j0 = (blockIdx.x & 3) * 64;
  const int t = threadIdx.x;
  const int tx = t & 15, ty = t >> 4;
  const float* Ab = A + (size_t)b * 65536;
  const float* Bb = Bm + (size_t)b * 65536;
  __shared__ float sa[16][68];  // k-major (A transposed on load), 272B rows
  __shared__ float sb[16][68];
  float acc[4][4] = {};
  const int li = t >> 2, lk4 = (t & 3) * 4;   // A tile load
  const int lk = t >> 4, lj4 = (t & 15) * 4;  // B tile load
  for (int k0 = 0; k0 < 256; k0 += 16) {
    __syncthreads();
    float4 av = *(const float4*)&Ab[(i0 + li) * 256 + k0 + lk4];
    sa[lk4 + 0][li] = av.x; sa[lk4 + 1][li] = av.y;
    sa[lk4 + 2][li] = av.z; sa[lk4 + 3][li] = av.w;
    *(float4*)&sb[lk][lj4] = *(const float4*)&Bb[(k0 + lk) * 256 + j0 + lj4];
    __syncthreads();
#pragma unroll
    for (int kk = 0; kk < 16; ++kk) {
      float4 a4 = *(const float4*)&sa[kk][ty * 4];
      float4 b4 = *(const float4*)&sb[kk][tx * 4];
      float avv[4] = {a4.x, a4.y, a4.z, a4.w};
      float bvv[4] = {b4.x, b4.y, b4.z, b4.w};
#pragma unroll
      for (int o = 0; o < 4; ++o)
#pragma unroll
        for (int j = 0; j < 4; ++j) acc[o][j] += avv[o] * bvv[j];
    }
  }
#pragma unroll
  for (int o = 0; o < 4; ++o) {
    float4 r;
    r.x = acc[o][0]; r.y = acc[o][1]; r.z = acc[o][2]; r.w = acc[o][3];
    *(float4*)&Cm[((size_t)b * 256 + i0 + ty * 4 + o) * 256 + j0 + tx * 4] = r;
  }
}

__global__ __launch_bounds__(256) void minmax_k(const float* __restrict__ x,
                                                unsigned* __restrict__ mm)
{
  const int idx = blockIdx.x * 256 + threadIdx.x;
  float mn = INFINITY, mx = -INFINITY;
  for (int i = idx; i < 2097152; i += gridDim.x * 256) {
    float v = x[i];
    mn = fminf(mn, v); mx = fmaxf(mx, v);
  }
#pragma unroll
  for (int off = 32; off; off >>= 1) {
    mn = fminf(mn, __shfl_down(mn, off));
    mx = fmaxf(mx, __shfl_down(mx, off));
  }
  __shared__ float smn[4], smx[4];
  const int wid = threadIdx.x >> 6, lane = threadIdx.x & 63;
  if (lane == 0) { smn[wid] = mn; smx[wid] = mx; }
  __syncthreads();
  if (threadIdx.x == 0) {
    mn = fminf(fminf(smn[0], smn[1]), fminf(smn[2], smn[3]));
    mx = fmaxf(fmaxf(smx[0], smx[1]), fmaxf(smx[2], smx[3]));
    atomicMin(&mm[0], mapf(mn));
    atomicMax(&mm[1], mapf(mx));
  }
}

// Per (b, phase): 256->1ch 3x3 conv partial. phase 0: normalized rec2 with
// w_val[0:256]; phase 1/2: con_feat[:,m] with w_val[256:512]. grid (32,3).
__global__ __launch_bounds__(256) void score_conv_k(
    const float* __restrict__ rec2, const float* __restrict__ cf,
    const float* __restrict__ wval, const unsigned* __restrict__ mm,
    float* __restrict__ sraw)
{
  const int b = blockIdx.x, phase = blockIdx.y;
  const int t = threadIdx.x;
  const int row = t >> 4, col = t & 15;
  __shared__ float s_in[8 * 360];
  __shared__ float s_wv[72];
  for (int i = t; i < 8 * 360; i += 256) s_in[i] = 0.f;
  const float* src;
  float sc = 1.f, sh = 0.f;
  int wofs;
  if (phase == 0) {
    src = rec2 + (size_t)b * 65536;
    float mn = unmapf(mm[0]), mx = unmapf(mm[1]);
    sc = 2.f / (mx - mn);
    sh = -mn * sc - 1.f;
    wofs = 0;
  } else {
    src = cf + ((size_t)b * 2 + (phase - 1)) * 65536;
    wofs = 2304;
  }
  float acc = 0.f;
  for (int ic0 = 0; ic0 < 256; ic0 += 8) {
    __syncthreads();
#pragma unroll
    for (int i = 0; i < 8; ++i) {
      float v = src[(ic0 + i) * 256 + t];
      if (phase == 0) v = fmaf(v, sc, sh);
      s_in[i * 360 + (row + 1) * 20 + (col + 1)] = v;
    }
    if (t < 72) s_wv[t] = wval[wofs + ic0 * 9 + t];
    __syncthreads();
#pragma unroll
    for (int i = 0; i < 8; ++i)
#pragma unroll
      for (int ky = 0; ky < 3; ++ky)
#pragma unroll
        for (int kx = 0; kx < 3; ++kx)
          acc += s_in[i * 360 + (row + ky) * 20 + (col + kx)] * s_wv[i * 9 + ky * 3 + kx];
  }
  sraw[((size_t)b * 3 + phase) * 256 + t] = acc;
}

__global__ void fuse_k(const float* __restrict__ cf, const float* __restrict__ rec2,
                       const float* __restrict__ sraw, const float* __restrict__ bval,
                       const unsigned* __restrict__ mm, const float* __restrict__ lacc,
                       float* __restrict__ outp)
{
  const int idx = blockIdx.x * 256 + threadIdx.x;
  const int b = idx >> 16;
  const int rest = idx & 65535;
  const int pos = idx & 255;
  const float mn = unmapf(mm[0]), mx = unmapf(mm[1]);
  const float sc = 2.f / (mx - mn), sh = -mn * sc - 1.f;
  const float srec = sraw[(size_t)b * 768 + pos];
  const float sc0 = sraw[(size_t)b * 768 + 256 + pos];
  const float sc1 = sraw[(size_t)b * 768 + 512 + pos];
  const float bv = bval[0];
  const float z0 = fmaxf(srec + sc0 + bv, 0.f);
  const float z1 = fmaxf(srec + sc1 + bv, 0.f);
  const float s0 = 1.f / (1.f + expf(-z0));
  const float s1 = 1.f / (1.f + expf(-z1));
  const float w0 = 1.f / (1.f + expf(s1 - s0));  // softmax over 2 modalities
  const float w1 = 1.f - w0;
  const float rn = fmaf(rec2[idx], sc, sh);
  const float f0 = cf[(size_t)b * 131072 + rest];
  const float f1 = cf[(size_t)b * 131072 + 65536 + rest];
  outp[idx] = 0.2f * (w0 * f0 + w1 * f1) + 0.8f * rn;
  if (idx == 0) outp[2097152] = lacc[0] * (1.f / 4194304.f);
}

extern "C" void kernel_launch(void* const* d_in, const int* in_sizes, int n_in,
                              void* d_out, int out_size, void* d_ws, size_t ws_size,
                              hipStream_t stream) {
  const float* cf    = (const float*)d_in[0];
  const float* fs    = (const float*)d_in[1];
  const float* fv    = (const float*)d_in[2];
  const float* fd    = (const float*)d_in[3];
  const float* w_enc = (const float*)d_in[4];
  const float* b_enc = (const float*)d_in[5];
  const float* w_dec = (const float*)d_in[6];
  const float* b_dec = (const float*)d_in[7];
  const float* w_val = (const float*)d_in[8];
  const float* b_val = (const float*)d_in[9];
  float* out = (float*)d_out;
  float* wsf = (float*)d_ws;

  // ws layout (floats). mid dead after the loss conv; A/Bm reuse its space.
  float* mid  = wsf;                          // 4,194,304  (64,256,16,16)
  float* A    = wsf;                          // 2,097,152  (32,256,256)
  float* Bm   = wsf + 2097152;                // 2,097,152
  float* rec  = wsf + 4194304;                // 2,097,152
  float* rec2 = wsf + 6291456;                // 2,097,152
  float* sraw = wsf + 8388608;                // 24,576 (32,3,256)
  float* vd   = wsf + 8413184;                // 8,192
  float* lacc = wsf + 8421376;                // 1
  int*   smr  = (int*)(wsf + 8421377);        // 8,192
  unsigned* mm = (unsigned*)(wsf + 8429569);  // 2

  init_k<<<1, 1, 0, stream>>>(lacc, mm);
  // encoder: relu(conv(x, w_enc) + b_enc)
  conv3x3_k<true, false><<<dim3(8, 64), 256, 0, stream>>>(cf, w_enc, b_enc, nullptr, mid, lacc);
  // decoder + fused reconstruction-loss reduction (x_rec not materialized)
  conv3x3_k<false, true><<<dim3(8, 64), 256, 0, stream>>>(mid, w_dec, b_dec, cf, nullptr, lacc);
  // rank budget + slot maps
  slots_k<<<32, 256, 0, stream>>>(fv, smr, vd);
  // A = ns * diag(vd), Bm = nd  (rec = A @ Bm collapses ns@nv@nd)
  assemble_k<<<dim3(16, 32), 256, 0, stream>>>(fs, fd, smr, vd, A, Bm);
  gemm_k<<<dim3(16, 32), 256, 0, stream>>>(A, Bm, rec);
  // decoder on rec
  conv3x3_k<false, false><<<dim3(8, 32), 256, 0, stream>>>(rec, w_dec, b_dec, nullptr, rec2, lacc);
  minmax_k<<<512, 256, 0, stream>>>(rec2, mm);
  // value-conv: shared rec half + per-modality halves
  score_conv_k<<<dim3(32, 3), 256, 0, stream>>>(rec2, cf, w_val, mm, sraw);
  fuse_k<<<8192, 256, 0, stream>>>(cf, rec2, sraw, b_val, mm, lacc, out);
}

// Round 2
// 316.532 us; speedup vs baseline: 5.6797x; 5.6797x over previous
//
#include <hip/hip_runtime.h>
#include <math.h>

// Shapes (fixed): B=32, M=2, C=256, H=W=16, N=256, DIM=256, THR=0.1, RATIO=0.8
// out: fused (32,256,16,16) = 2,097,152 floats, then auto_enc_loss (1 float)
//
// Strategy: all 256->256 3x3 convs as bf16 implicit GEMM (MFMA 16x16x32),
// inputs in padded NHWC bf16 (1-px zero halo) so im2col rows are contiguous
// 256-ch slices -> global_load_lds width-16 staging. XOR chunk swizzle keeps
// ds_read_b128 conflict-free while LDS stays DMA-contiguous.

typedef __attribute__((ext_vector_type(8))) short short8;
typedef __attribute__((ext_vector_type(4))) float f32x4;

__device__ __forceinline__ void gload_lds16(const void* g, void* l) {
  __builtin_amdgcn_global_load_lds(
      (const __attribute__((address_space(1))) void*)g,
      (__attribute__((address_space(3))) void*)l, 16, 0, 0);
}

__device__ __forceinline__ unsigned short f2bf(float f) {
  unsigned u = __float_as_uint(f);
  unsigned r = (u + 0x7FFFu + ((u >> 16) & 1u)) >> 16;  // RNE
  return (unsigned short)r;
}

__device__ __forceinline__ unsigned mapf(float f) {
  unsigned u = __float_as_uint(f);
  return (u & 0x80000000u) ? ~u : (u | 0x80000000u);   // monotone float->uint
}
__device__ __forceinline__ float unmapf(unsigned u) {
  unsigned v = (u & 0x80000000u) ? (u & 0x7fffffffu) : ~u;
  return __uint_as_float(v);
}

__global__ void init_k(float* lacc, unsigned* mm) {
  lacc[0] = 0.f;
  mm[0] = 0xFFFFFFFFu;  // min accumulator (mapped)
  mm[1] = 0u;           // max accumulator (mapped)
}

__global__ void zero_k(float4* p, int n4) {
  int i = blockIdx.x * 256 + threadIdx.x;
  if (i < n4) p[i] = make_float4(0.f, 0.f, 0.f, 0.f);
}

// cf (img,C,16,16) fp32 -> Xp (img,18,18,256) bf16, interior only (halo pre-zeroed)
__global__ __launch_bounds__(256) void pack_k(const float* __restrict__ cf,
                                              unsigned short* __restrict__ Xp) {
  int idx = blockIdx.x * 256 + threadIdx.x;      // 64*256*32 threads
  int ch = idx & 31, p = (idx >> 5) & 255, img = idx >> 13;
  int ic0 = ch * 8;
  const float* sp = cf + (size_t)img * 65536 + (size_t)ic0 * 256 + p;
  unsigned short h[8];
#pragma unroll
  for (int i = 0; i < 8; ++i) h[i] = f2bf(sp[i * 256]);
  int y = p >> 4, x = p & 15;
  uint4 u;
  u.x = h[0] | (h[1] << 16); u.y = h[2] | (h[3] << 16);
  u.z = h[4] | (h[5] << 16); u.w = h[6] | (h[7] << 16);
  *(uint4*)&Xp[(size_t)img * 82944 + (size_t)(y * 18 + x + 19) * 256 + ic0] = u;
}

// OIHW fp32 -> Wr[oc][s][ic] bf16 for enc+dec (s = ky*3+kx)
__global__ __launch_bounds__(256) void wrk_k(const float* __restrict__ we,
                                             const float* __restrict__ wd,
                                             unsigned short* __restrict__ WrE,
                                             unsigned short* __restrict__ WrD) {
  int idx = blockIdx.x * 256 + threadIdx.x;      // 2*256*9*32 = 147456
  int ch = idx & 31, rest = idx >> 5;
  int s = rest % 9, ocx = rest / 9;
  int oc = ocx & 255, cv = ocx >> 8;
  const float* w = cv ? wd : we;
  unsigned short* o = cv ? WrD : WrE;
  int ic0 = ch * 8;
  unsigned short h[8];
#pragma unroll
  for (int i = 0; i < 8; ++i) h[i] = f2bf(w[(size_t)oc * 2304 + (ic0 + i) * 9 + s]);
  uint4 u;
  u.x = h[0] | (h[1] << 16); u.y = h[2] | (h[3] << 16);
  u.z = h[4] | (h[5] << 16); u.w = h[6] | (h[7] << 16);
  *(uint4*)&o[(size_t)oc * 2304 + s * 256 + ic0] = u;
}

// Per-batch slot maps (validated round 1)
__global__ __launch_bounds__(256) void slots_k(const float* __restrict__ fv,
                                               int* __restrict__ smr,
                                               float* __restrict__ vd) {
  const int b = blockIdx.x, t = threadIdx.x;
  const float v0 = fv[(size_t)b * 512 + t];
  const float v1 = fv[(size_t)b * 512 + 256 + t];
  const unsigned long long bal0 = __ballot(v0 > 0.1f);
  const unsigned long long bal1 = __ballot(v1 > 0.1f);
  __shared__ int cnt0[4], cnt1[4], fc[2];
  const int wid = t >> 6, lane = t & 63;
  if (lane == 0) { cnt0[wid] = __popcll(bal0); cnt1[wid] = __popcll(bal1); }
  smr[b * 256 + t] = -1;
  vd[b * 256 + t] = 0.f;
  __syncthreads();
  if (t == 0) {
    int c0 = cnt0[0] + cnt0[1] + cnt0[2] + cnt0[3];
    int c1 = cnt1[0] + cnt1[1] + cnt1[2] + cnt1[3];
    int total = c0 + c1;
    int f0, f1;
    if (total > 256) {
      int a0 = (int)rintf(256.0f * (float)c0 / (float)total);
      f0 = a0; f1 = 256 - a0;
    } else { f0 = c0; f1 = c1; }
    fc[0] = max(f0, 0); fc[1] = max(f1, 0);
  }
  __syncthreads();
  const int c0 = fc[0], c1 = fc[1];
  if (t < c0) { smr[b * 256 + t] = t; vd[b * 256 + t] = v0; }
  if (t < c1) {
    int d = c0 + t;
    if (d < 256) { smr[b * 256 + d] = 256 + t; vd[b * 256 + d] = v1; }
  }
}

// Ans[b][c][j] = ns[c][j]*v_j (bf16, k-contiguous rows)
__global__ __launch_bounds__(256) void ansb_k(const float* __restrict__ fs,
                                              const int* __restrict__ smr,
                                              const float* __restrict__ vd,
                                              unsigned short* __restrict__ Ans) {
  int idx = blockIdx.x * 256 + threadIdx.x;      // 32*256*32
  int ch = idx & 31, c = (idx >> 5) & 255, b = idx >> 13;
  int j0 = ch * 8;
  int si = smr[b * 256 + c];
  unsigned short h[8] = {0, 0, 0, 0, 0, 0, 0, 0};
  if (si >= 0) {
    int m = si >> 8, r = si & 255;
    const float* fp = fs + (((size_t)b * 2 + m) * 256 + r) * 256 + j0;
    const float* vp = vd + b * 256 + j0;
#pragma unroll
    for (int i = 0; i < 8; ++i) h[i] = f2bf(fp[i] * vp[i]);
  }
  uint4 u;
  u.x = h[0] | (h[1] << 16); u.y = h[2] | (h[3] << 16);
  u.z = h[4] | (h[5] << 16); u.w = h[6] | (h[7] << 16);
  *(uint4*)&Ans[(size_t)b * 65536 + c * 256 + j0] = u;
}

// BmT[b][p][j] = fd[b, m_p, j, r_p] (bf16, k-contiguous rows)
__global__ __launch_bounds__(256) void bmt_k(const float* __restrict__ fd,
                                             const int* __restrict__ smr,
                                             unsigned short* __restrict__ BmT) {
  int idx = blockIdx.x * 256 + threadIdx.x;      // 32*256*32
  int ch = idx & 31, p = (idx >> 5) & 255, b = idx >> 13;
  int j0 = ch * 8;
  int sp = smr[b * 256 + p];
  unsigned short h[8] = {0, 0, 0, 0, 0, 0, 0, 0};
  if (sp >= 0) {
    int m = sp >> 8, r = sp & 255;
    const float* base = fd + (((size_t)b * 2 + m) * 256 + j0) * 256 + r;
#pragma unroll
    for (int i = 0; i < 8; ++i) h[i] = f2bf(base[i * 256]);
  }
  uint4 u;
  u.x = h[0] | (h[1] << 16); u.y = h[2] | (h[3] << 16);
  u.z = h[4] | (h[5] << 16); u.w = h[6] | (h[7] << 16);
  *(uint4*)&BmT[(size_t)b * 65536 + p * 256 + j0] = u;
}

// ---------------- MFMA conv: implicit GEMM, out[p][oc] = sum_k X[p][k]W[oc][k]
// grid (4, nimg): blockIdx.x = pt*2 + ot. Tile 128(px) x 128(oc), BK=64.
// EPI: 0=enc(relu->NHWC bf16), 1=dec+loss, 2=dec(rec)->NCHW f32 + minmax
template<int EPI>
__global__ __launch_bounds__(256) void convmma_k(
    const unsigned short* __restrict__ Xin, const unsigned short* __restrict__ Wr,
    const float* __restrict__ bias, const float* __restrict__ cfref,
    unsigned short* __restrict__ outp, float* __restrict__ outf,
    float* __restrict__ lacc, unsigned* __restrict__ mm) {
  __shared__ __align__(16) unsigned short As[8192];  // [128 rows][64 k] swizzled
  __shared__ __align__(16) unsigned short Bs[8192];
  const int t = threadIdx.x, lane = t & 63, wave = t >> 6;
  const int img = blockIdx.y, pt = blockIdx.x >> 1, ot = blockIdx.x & 1;

  // staging lane constants (global byte offsets, minus per-iter scalar part)
  int laneA[4], laneB[4];
  {
    const int r8 = t >> 3, sub = t & 7;
#pragma unroll
    for (int j = 0; j < 4; ++j) {
      int row = j * 32 + r8;
      int p = pt * 128 + row;
      int y = p >> 4, x = p & 15;
      int qg = (sub ^ (row & 7)) * 16;
      laneA[j] = (y * 18 + x) * 512 + qg;
      laneB[j] = (ot * 128 + row) * 4608 + qg;
    }
  }
  const char* Ag = (const char*)Xin + (size_t)img * 165888;
  const char* Bg = (const char*)Wr;

  // ds-read byte offsets (loop-invariant; XOR-swizzled chunk positions)
  const int mlane = lane & 15, quad = lane >> 4;
  const int mw = wave >> 1, nw = wave & 1;
  int aoff[4][2], boff[4][2];
#pragma unroll
  for (int i = 0; i < 4; ++i) {
    int rowm = mw * 64 + i * 16 + mlane;
    int rown = nw * 64 + i * 16 + mlane;
#pragma unroll
    for (int ks = 0; ks < 2; ++ks) {
      aoff[i][ks] = rowm * 128 + (((ks * 4 + quad) ^ (rowm & 7)) * 16);
      boff[i][ks] = rown * 128 + (((ks * 4 + quad) ^ (rown & 7)) * 16);
    }
  }

  f32x4 acc[4][4] = {};

  for (int kit = 0; kit < 36; ++kit) {
    int s = kit >> 2;
    int dy = s / 3, dx = s - dy * 3;
    int aG = (dy * 18 + dx) * 512 + ((kit & 3) << 7);
    int bG = kit << 7;
    __syncthreads();
#pragma unroll
    for (int j = 0; j < 4; ++j)
      gload_lds16(Ag + laneA[j] + aG, (char*)As + j * 4096 + wave * 1024);
#pragma unroll
    for (int j = 0; j < 4; ++j)
      gload_lds16(Bg + laneB[j] + bG, (char*)Bs + j * 4096 + wave * 1024);
    __syncthreads();
#pragma unroll
    for (int ks = 0; ks < 2; ++ks) {
      short8 af[4], bf[4];
#pragma unroll
      for (int i = 0; i < 4; ++i) {
        af[i] = *(const short8*)((const char*)As + aoff[i][ks]);
        bf[i] = *(const short8*)((const char*)Bs + boff[i][ks]);
      }
#pragma unroll
      for (int i = 0; i < 4; ++i)
#pragma unroll
        for (int n = 0; n < 4; ++n)
          acc[i][n] = __builtin_amdgcn_mfma_f32_16x16x32_bf16(af[i], bf[n], acc[i][n], 0, 0, 0);
    }
  }

  // epilogue
  if (EPI == 0) {
#pragma unroll
    for (int i = 0; i < 4; ++i) {
      int m0 = pt * 128 + mw * 64 + i * 16 + quad * 4;
#pragma unroll
      for (int n = 0; n < 4; ++n) {
        int oc = ot * 128 + nw * 64 + n * 16 + mlane;
        float bv = bias[oc];
#pragma unroll
        for (int r = 0; r < 4; ++r) {
          int p = m0 + r;
          int y = p >> 4, x = p & 15;
          float v = fmaxf(acc[i][n][r] + bv, 0.f);
          outp[(size_t)img * 82944 + (size_t)(y * 18 + x + 19) * 256 + oc] = f2bf(v);
        }
      }
    }
  } else if (EPI == 1) {
    float ls = 0.f;
#pragma unroll
    for (int i = 0; i < 4; ++i) {
      int m0 = pt * 128 + mw * 64 + i * 16 + quad * 4;
#pragma unroll
      for (int n = 0; n < 4; ++n) {
        int oc = ot * 128 + nw * 64 + n * 16 + mlane;
        float bv = bias[oc];
        float4 c4 = *(const float4*)(cfref + (size_t)img * 65536 + (size_t)oc * 256 + m0);
        float d0 = acc[i][n][0] + bv - c4.x;
        float d1 = acc[i][n][1] + bv - c4.y;
        float d2 = acc[i][n][2] + bv - c4.z;
        float d3 = acc[i][n][3] + bv - c4.w;
        ls += d0 * d0 + d1 * d1 + d2 * d2 + d3 * d3;
      }
    }
#pragma unroll
    for (int off = 32; off; off >>= 1) ls += __shfl_down(ls, off);
    __shared__ float sred[4];
    if (lane == 0) sred[wave] = ls;
    __syncthreads();
    if (t == 0) atomicAdd(lacc, sred[0] + sred[1] + sred[2] + sred[3]);
  } else {
    float mn = INFINITY, mx = -INFINITY;
#pragma unroll
    for (int i = 0; i < 4; ++i) {
      int m0 = pt * 128 + mw * 64 + i * 16 + quad * 4;
#pragma unroll
      for (int n = 0; n < 4; ++n) {
        int oc = ot * 128 + nw * 64 + n * 16 + mlane;
        float bv = bias[oc];
        float4 v;
        v.x = acc[i][n][0] + bv; v.y = acc[i][n][1] + bv;
        v.z = acc[i][n][2] + bv; v.w = acc[i][n][3] + bv;
        mn = fminf(mn, fminf(fminf(v.x, v.y), fminf(v.z, v.w)));
        mx = fmaxf(mx, fmaxf(fmaxf(v.x, v.y), fmaxf(v.z, v.w)));
        *(float4*)(outf + (size_t)img * 65536 + (size_t)oc * 256 + m0) = v;
      }
    }
#pragma unroll
    for (int off = 32; off; off >>= 1) {
      mn = fminf(mn, __shfl_down(mn, off));
      mx = fmaxf(mx, __shfl_down(mx, off));
    }
    __shared__ float smn[4], smx[4];
    if (lane == 0) { smn[wave] = mn; smx[wave] = mx; }
    __syncthreads();
    if (t == 0) {
      mn = fminf(fminf(smn[0], smn[1]), fminf(smn[2], smn[3]));
      mx = fmaxf(fmaxf(smx[0], smx[1]), fmaxf(smx[2], smx[3]));
      atomicMin(&mm[0], mapf(mn));
      atomicMax(&mm[1], mapf(mx));
    }
  }
}

// rec^T[p][c] = sum_j BmT[p][j]*Ans[c][j]  -> Recp padded NHWC bf16
// grid (4, 32): blockIdx.x = pt*2 + ct
__global__ __launch_bounds__(256) void recgemm_k(const unsigned short* __restrict__ BmT,
                                                 const unsigned short* __restrict__ Ans,
                                                 unsigned short* __restrict__ Recp) {
  __shared__ __align__(16) unsigned short As[8192];
  __shared__ __align__(16) unsigned short Bs[8192];
  const int t = threadIdx.x, lane = t & 63, wave = t >> 6;
  const int b = blockIdx.y, pt = blockIdx.x >> 1, ct = blockIdx.x & 1;

  int laneA[4], laneB[4];
  {
    const int r8 = t >> 3, sub = t & 7;
#pragma unroll
    for (int j = 0; j < 4; ++j) {
      int row = j * 32 + r8;
      int qg = (sub ^ (row & 7)) * 16;
      laneA[j] = (pt * 128 + row) * 512 + qg;
      laneB[j] = (ct * 128 + row) * 512 + qg;
    }
  }
  const char* Ag = (const char*)BmT + (size_t)b * 131072;
  const char* Bg = (const char*)Ans + (size_t)b * 131072;

  const int mlane = lane & 15, quad = lane >> 4;
  const int mw = wave >> 1, nw = wave & 1;
  int aoff[4][2], boff[4][2];
#pragma unroll
  for (int i = 0; i < 4; ++i) {
    int rowm = mw * 64 + i * 16 + mlane;
    int rown = nw * 64 + i * 16 + mlane;
#pragma unroll
    for (int ks = 0; ks < 2; ++ks) {
      aoff[i][ks] = rowm * 128 + (((ks * 4 + quad) ^ (rowm & 7)) * 16);
      boff[i][ks] = rown * 128 + (((ks * 4 + quad) ^ (rown & 7)) * 16);
    }
  }

  f32x4 acc[4][4] = {};

  for (int kit = 0; kit < 4; ++kit) {
    int g = kit << 7;
    __syncthreads();
#pragma unroll
    for (int j = 0; j < 4; ++j)
      gload_lds16(Ag + laneA[j] + g, (char*)As + j * 4096 + wave * 1024);
#pragma unroll
    for (int j = 0; j < 4; ++j)
      gload_lds16(Bg + laneB[j] + g, (char*)Bs + j * 4096 + wave * 1024);
    __syncthreads();
#pragma unroll
    for (int ks = 0; ks < 2; ++ks) {
      short8 af[4], bf[4];
#pragma unroll
      for (int i = 0; i < 4; ++i) {
        af[i] = *(const short8*)((const char*)As + aoff[i][ks]);
        bf[i] = *(const short8*)((const char*)Bs + boff[i][ks]);
      }
#pragma unroll
      for (int i = 0; i < 4; ++i)
#pragma unroll
        for (int n = 0; n < 4; ++n)
          acc[i][n] = __builtin_amdgcn_mfma_f32_16x16x32_bf16(af[i], bf[n], acc[i][n], 0, 0, 0);
    }
  }

#pragma unroll
  for (int i = 0; i < 4; ++i) {
    int m0 = pt * 128 + mw * 64 + i * 16 + quad * 4;
#pragma unroll
    for (int n = 0; n < 4; ++n) {
      int cc = ct * 128 + nw * 64 + n * 16 + mlane;
#pragma unroll
      for (int r = 0; r < 4; ++r) {
        int p = m0 + r;
        int y = p >> 4, x = p & 15;
        Recp[(size_t)b * 82944 + (size_t)(y * 18 + x + 19) * 256 + cc] = f2bf(acc[i][n][r]);
      }
    }
  }
}

// 256->1 score conv partials, ic-split 4-way, atomicAdd into sraw (pre-zeroed)
__global__ __launch_bounds__(256) void score_conv_k(
    const float* __restrict__ rec2, const float* __restrict__ cf,
    const float* __restrict__ wval, const unsigned* __restrict__ mm,
    float* __restrict__ sraw) {
  const int b = blockIdx.x, phase = blockIdx.y, icc = blockIdx.z;
  const int t = threadIdx.x;
  const int row = t >> 4, col = t & 15;
  __shared__ float s_in[8 * 360];
  __shared__ float s_wv[72];
  for (int i = t; i < 8 * 360; i += 256) s_in[i] = 0.f;
  const float* src;
  float sc = 1.f, sh = 0.f;
  int wofs;
  if (phase == 0) {
    src = rec2 + (size_t)b * 65536;
    float mn = unmapf(mm[0]), mx = unmapf(mm[1]);
    sc = 2.f / (mx - mn);
    sh = -mn * sc - 1.f;
    wofs = 0;
  } else {
    src = cf + ((size_t)b * 2 + (phase - 1)) * 65536;
    wofs = 2304;
  }
  float acc = 0.f;
  for (int ic0 = icc * 64; ic0 < icc * 64 + 64; ic0 += 8) {
    __syncthreads();
#pragma unroll
    for (int i = 0; i < 8; ++i) {
      float v = src[(ic0 + i) * 256 + t];
      if (phase == 0) v = fmaf(v, sc, sh);
      s_in[i * 360 + (row + 1) * 20 + (col + 1)] = v;
    }
    if (t < 72) s_wv[t] = wval[wofs + ic0 * 9 + t];
    __syncthreads();
#pragma unroll
    for (int i = 0; i < 8; ++i)
#pragma unroll
      for (int ky = 0; ky < 3; ++ky)
#pragma unroll
        for (int kx = 0; kx < 3; ++kx)
          acc += s_in[i * 360 + (row + ky) * 20 + (col + kx)] * s_wv[i * 9 + ky * 3 + kx];
  }
  atomicAdd(&sraw[((size_t)b * 3 + phase) * 256 + t], acc);
}

__global__ void fuse_k(const float* __restrict__ cf, const float* __restrict__ rec2,
                       const float* __restrict__ sraw, const float* __restrict__ bval,
                       const unsigned* __restrict__ mm, const float* __restrict__ lacc,
                       float* __restrict__ outp) {
  const int idx = blockIdx.x * 256 + threadIdx.x;
  const int b = idx >> 16;
  const int rest = idx & 65535;
  const int pos = idx & 255;
  const float mn = unmapf(mm[0]), mx = unmapf(mm[1]);
  const float sc = 2.f / (mx - mn), sh = -mn * sc - 1.f;
  const float srec = sraw[(size_t)b * 768 + pos];
  const float sc0 = sraw[(size_t)b * 768 + 256 + pos];
  const float sc1 = sraw[(size_t)b * 768 + 512 + pos];
  const float bv = bval[0];
  const float z0 = fmaxf(srec + sc0 + bv, 0.f);
  const float z1 = fmaxf(srec + sc1 + bv, 0.f);
  const float s0 = 1.f / (1.f + expf(-z0));
  const float s1 = 1.f / (1.f + expf(-z1));
  const float w0 = 1.f / (1.f + expf(s1 - s0));  // softmax over 2 modalities
  const float w1 = 1.f - w0;
  const float rn = fmaf(rec2[idx], sc, sh);
  const float f0 = cf[(size_t)b * 131072 + rest];
  const float f1 = cf[(size_t)b * 131072 + 65536 + rest];
  outp[idx] = 0.2f * (w0 * f0 + w1 * f1) + 0.8f * rn;
  if (idx == 0) outp[2097152] = lacc[0] * (1.f / 4194304.f);
}

extern "C" void kernel_launch(void* const* d_in, const int* in_sizes, int n_in,
                              void* d_out, int out_size, void* d_ws, size_t ws_size,
                              hipStream_t stream) {
  const float* cf    = (const float*)d_in[0];
  const float* fs    = (const float*)d_in[1];
  const float* fv    = (const float*)d_in[2];
  const float* fd    = (const float*)d_in[3];
  const float* w_enc = (const float*)d_in[4];
  const float* b_enc = (const float*)d_in[5];
  const float* w_dec = (const float*)d_in[6];
  const float* b_dec = (const float*)d_in[7];
  const float* w_val = (const float*)d_in[8];
  const float* b_val = (const float*)d_in[9];
  float* out = (float*)d_out;
  float* wsf = (float*)d_ws;

  // ws layout (float offsets). Aliases:
  //   Xp (64 img padded NHWC bf16)   [0, 2654208)   -- dead after enc conv
  //     Ans bf16 (32x256x256) @0, BmT bf16 @1048576  (written after enc conv)
  //   Midp (64 img padded NHWC bf16) [2654208, 5308416) -- dead after loss conv
  //     Recp (32 img padded NHWC bf16) @2654208 (re-zeroed after loss conv)
  unsigned short* Xp   = (unsigned short*)wsf;
  unsigned short* Ans  = (unsigned short*)wsf;
  unsigned short* BmT  = (unsigned short*)(wsf + 1048576);
  unsigned short* Midp = (unsigned short*)(wsf + 2654208);
  unsigned short* Recp = (unsigned short*)(wsf + 2654208);
  float* rec2 = wsf + 5308416;                    // 2,097,152 (NCHW f32)
  unsigned short* WrE = (unsigned short*)(wsf + 7405568);   // 294,912 fl
  unsigned short* WrD = (unsigned short*)(wsf + 7700480);   // 294,912 fl
  float* sraw = wsf + 7995392;                    // 24,576
  float* vd   = wsf + 8019968;                    // 8,192
  int*   smr  = (int*)(wsf + 8028160);            // 8,192
  float* lacc = wsf + 8036352;
  unsigned* mm = (unsigned*)(wsf + 8036354);

  init_k<<<1, 1, 0, stream>>>(lacc, mm);
  zero_k<<<5184, 256, 0, stream>>>((float4*)wsf, 1327104);            // Xp+Midp halos
  zero_k<<<24, 256, 0, stream>>>((float4*)sraw, 6144);                // sraw
  wrk_k<<<576, 256, 0, stream>>>(w_enc, w_dec, WrE, WrD);
  pack_k<<<2048, 256, 0, stream>>>(cf, Xp);
  slots_k<<<32, 256, 0, stream>>>(fv, smr, vd);
  // encoder: relu(conv(x)) -> Midp
  convmma_k<0><<<dim3(4, 64), 256, 0, stream>>>(Xp, WrE, b_enc, nullptr, Midp, nullptr, nullptr, nullptr);
  // decoder + fused loss (x_rec not materialized)
  convmma_k<1><<<dim3(4, 64), 256, 0, stream>>>(Midp, WrD, b_dec, cf, nullptr, nullptr, lacc, nullptr);
  // Recp region (aliases Midp) re-zeroed for halo
  zero_k<<<1296, 256, 0, stream>>>((float4*)Recp, 331776);
  ansb_k<<<1024, 256, 0, stream>>>(fs, smr, vd, Ans);
  bmt_k<<<1024, 256, 0, stream>>>(fd, smr, BmT);
  recgemm_k<<<dim3(4, 32), 256, 0, stream>>>(BmT, Ans, Recp);
  // decoder on rec -> rec2 (NCHW f32) + fused min/max
  convmma_k<2><<<dim3(4, 32), 256, 0, stream>>>(Recp, WrD, b_dec, nullptr, nullptr, rec2, nullptr, mm);
  score_conv_k<<<dim3(32, 3, 4), 256, 0, stream>>>(rec2, cf, w_val, mm, sraw);
  fuse_k<<<8192, 256, 0, stream>>>(cf, rec2, sraw, b_val, mm, lacc, out);
}

// Round 3
// 252.971 us; speedup vs baseline: 7.1068x; 1.2513x over previous
//
#include <hip/hip_runtime.h>
#include <math.h>

// Shapes (fixed): B=32, M=2, C=256, H=W=16, N=256, DIM=256, THR=0.1, RATIO=0.8
// out: fused (32,256,16,16) = 2,097,152 floats, then auto_enc_loss (1 float)
//
// R3: convs as bf16 implicit GEMM, 64px x 128oc tiles, BK=128 (18 kits),
// 512 blocks = 2 blocks/CU for implicit stage/compute overlap (m114).
// bmt gather via LDS transpose; launches merged 14 -> 8.

typedef __attribute__((ext_vector_type(8))) short short8;
typedef __attribute__((ext_vector_type(4))) float f32x4;

__device__ __forceinline__ void gload_lds16(const void* g, void* l) {
  __builtin_amdgcn_global_load_lds(
      (const __attribute__((address_space(1))) void*)g,
      (__attribute__((address_space(3))) void*)l, 16, 0, 0);
}

__device__ __forceinline__ unsigned short f2bf(float f) {
  unsigned u = __float_as_uint(f);
  unsigned r = (u + 0x7FFFu + ((u >> 16) & 1u)) >> 16;  // RNE
  return (unsigned short)r;
}

__device__ __forceinline__ unsigned mapf(float f) {
  unsigned u = __float_as_uint(f);
  return (u & 0x80000000u) ? ~u : (u | 0x80000000u);   // monotone float->uint
}
__device__ __forceinline__ float unmapf(unsigned u) {
  unsigned v = (u & 0x80000000u) ? (u & 0x7fffffffu) : ~u;
  return __uint_as_float(v);
}

// ---------------- merged prep: pack | weight-repack | halo-zero | slots | init
// grid 2809: [0,2048) pack, [2048,2624) wrk, [2624,2752) halo(128 img),
//            [2752,2784) slots, [2784,2809) zero sraw + init
__global__ __launch_bounds__(256) void prep_k(
    const float* __restrict__ cf, const float* __restrict__ we,
    const float* __restrict__ wd, const float* __restrict__ fv,
    unsigned short* __restrict__ Xp, unsigned short* __restrict__ WrE,
    unsigned short* __restrict__ WrD, int* __restrict__ smr,
    float* __restrict__ vd, float4* __restrict__ sraw4,
    float* __restrict__ lacc, unsigned* __restrict__ mm) {
  const int bx = blockIdx.x, t = threadIdx.x;
  if (bx < 2048) {                       // pack: cf NCHW f32 -> padded NHWC bf16
    int idx = bx * 256 + t;
    int ch = idx & 31, p = (idx >> 5) & 255, img = idx >> 13;
    int ic0 = ch * 8;
    const float* sp = cf + (size_t)img * 65536 + (size_t)ic0 * 256 + p;
    unsigned short h[8];
#pragma unroll
    for (int i = 0; i < 8; ++i) h[i] = f2bf(sp[i * 256]);
    int y = p >> 4, x = p & 15;
    uint4 u;
    u.x = h[0] | (h[1] << 16); u.y = h[2] | (h[3] << 16);
    u.z = h[4] | (h[5] << 16); u.w = h[6] | (h[7] << 16);
    *(uint4*)&Xp[(size_t)img * 82944 + (size_t)(y * 18 + x + 19) * 256 + ic0] = u;
  } else if (bx < 2624) {                // wrk: OIHW f32 -> Wr[oc][s][ic] bf16
    int idx = (bx - 2048) * 256 + t;
    int ch = idx & 31, rest = idx >> 5;
    int s = rest % 9, ocx = rest / 9;
    int oc = ocx & 255, cv = ocx >> 8;
    const float* w = cv ? wd : we;
    unsigned short* o = cv ? WrD : WrE;
    int ic0 = ch * 8;
    unsigned short h[8];
#pragma unroll
    for (int i = 0; i < 8; ++i) h[i] = f2bf(w[(size_t)oc * 2304 + (ic0 + i) * 9 + s]);
    uint4 u;
    u.x = h[0] | (h[1] << 16); u.y = h[2] | (h[3] << 16);
    u.z = h[4] | (h[5] << 16); u.w = h[6] | (h[7] << 16);
    *(uint4*)&o[(size_t)oc * 2304 + s * 256 + ic0] = u;
  } else if (bx < 2752) {                // halo zero: Xp imgs 0..63, Midp 64..127
    int img = bx - 2624;
    uint4* base = (uint4*)Xp + (size_t)img * 10368;
    uint4 z; z.x = z.y = z.z = z.w = 0;
    for (int it = t; it < 2176; it += 256) {
      int px = it >> 5, c = it & 31;
      int y, x;
      if (px < 18)      { y = 0;  x = px; }
      else if (px < 36) { y = 17; x = px - 18; }
      else if (px < 52) { y = px - 35; x = 0; }
      else              { y = px - 51; x = 17; }
      base[(y * 18 + x) * 32 + c] = z;
    }
  } else if (bx < 2784) {                // slots: rank budget + dest maps
    const int b = bx - 2752;
    const float v0 = fv[(size_t)b * 512 + t];
    const float v1 = fv[(size_t)b * 512 + 256 + t];
    const unsigned long long bal0 = __ballot(v0 > 0.1f);
    const unsigned long long bal1 = __ballot(v1 > 0.1f);
    __shared__ int cnt0[4], cnt1[4], fc[2];
    const int wid = t >> 6, lane = t & 63;
    if (lane == 0) { cnt0[wid] = __popcll(bal0); cnt1[wid] = __popcll(bal1); }
    smr[b * 256 + t] = -1;
    vd[b * 256 + t] = 0.f;
    __syncthreads();
    if (t == 0) {
      int c0 = cnt0[0] + cnt0[1] + cnt0[2] + cnt0[3];
      int c1 = cnt1[0] + cnt1[1] + cnt1[2] + cnt1[3];
      int total = c0 + c1;
      int f0, f1;
      if (total > 256) {
        int a0 = (int)rintf(256.0f * (float)c0 / (float)total);
        f0 = a0; f1 = 256 - a0;
      } else { f0 = c0; f1 = c1; }
      fc[0] = max(f0, 0); fc[1] = max(f1, 0);
    }
    __syncthreads();
    const int c0 = fc[0], c1 = fc[1];
    if (t < c0) { smr[b * 256 + t] = t; vd[b * 256 + t] = v0; }
    if (t < c1) {
      int d = c0 + t;
      if (d < 256) { smr[b * 256 + d] = 256 + t; vd[b * 256 + d] = v1; }
    }
  } else {                               // zero sraw (24 blocks) + init (1)
    int z = bx - 2784;
    if (z < 24) {
      float4 zz; zz.x = zz.y = zz.z = zz.w = 0.f;
      sraw4[z * 256 + t] = zz;
    } else if (t == 0) {
      lacc[0] = 0.f; mm[0] = 0xFFFFFFFFu; mm[1] = 0u;
    }
  }
}

// ---------------- MFMA conv: out[p][oc] = sum_k X[p][k]W[oc][k]
// Tile 64px x 128oc, BK=128, 18 kits. grid (8, nimg): bx = pt*2 + ot.
// EPI: 0=enc(relu->NHWC bf16), 1=dec+loss, 2=dec(rec)->NCHW f32 + minmax
template<int EPI>
__global__ __launch_bounds__(256) void convmma_k(
    const unsigned short* __restrict__ Xin, const unsigned short* __restrict__ Wr,
    const float* __restrict__ bias, const float* __restrict__ cfref,
    unsigned short* __restrict__ outp, float* __restrict__ outf,
    float* __restrict__ lacc, unsigned* __restrict__ mm) {
  __shared__ __align__(16) unsigned short As[8192];    // 64 rows x 128k (16KB)
  __shared__ __align__(16) unsigned short Bs[16384];   // 128 rows x 128k (32KB)
  const int t = threadIdx.x, lane = t & 63, wave = t >> 6;
  const int img = blockIdx.y, pt = blockIdx.x >> 1, ot = blockIdx.x & 1;

  int laneA[4], laneB[8];
  {
    const int rl = lane >> 4, lc = lane & 15;
#pragma unroll
    for (int j = 0; j < 4; ++j) {
      int row = (wave * 4 + j) * 4 + rl;
      int p = pt * 64 + row;
      int y = p >> 4, x = p & 15;
      laneA[j] = (y * 18 + x) * 512 + ((lc ^ (row & 15)) * 16);
    }
#pragma unroll
    for (int j = 0; j < 8; ++j) {
      int row = (wave * 8 + j) * 4 + rl;
      laneB[j] = (ot * 128 + row) * 4608 + ((lc ^ (row & 15)) * 16);
    }
  }
  const char* Ag = (const char*)Xin + (size_t)img * 165888;
  const char* Bg = (const char*)Wr;

  const int mlane = lane & 15, quad = lane >> 4;
  const int mw = wave >> 1, nw = wave & 1;
  int aoff[2][4], boff[4][4];
#pragma unroll
  for (int ks = 0; ks < 4; ++ks) {
#pragma unroll
    for (int i = 0; i < 2; ++i) {
      int rowm = mw * 32 + i * 16 + mlane;
      aoff[i][ks] = rowm * 256 + (((ks * 4 + quad) ^ (rowm & 15)) * 16);
    }
#pragma unroll
    for (int n = 0; n < 4; ++n) {
      int rown = nw * 64 + n * 16 + mlane;
      boff[n][ks] = rown * 256 + (((ks * 4 + quad) ^ (rown & 15)) * 16);
    }
  }

  f32x4 acc[2][4] = {};

  for (int kit = 0; kit < 18; ++kit) {
    int s = kit >> 1, kc = kit & 1;
    int dy = s / 3, dx = s - dy * 3;
    int aG = (dy * 18 + dx) * 512 + kc * 256;
    int bG = kit << 8;
    __syncthreads();
#pragma unroll
    for (int j = 0; j < 4; ++j)
      gload_lds16(Ag + laneA[j] + aG, (char*)As + (wave * 4 + j) * 1024);
#pragma unroll
    for (int j = 0; j < 8; ++j)
      gload_lds16(Bg + laneB[j] + bG, (char*)Bs + (wave * 8 + j) * 1024);
    __syncthreads();
#pragma unroll
    for (int ks = 0; ks < 4; ++ks) {
      short8 af[2], bf[4];
#pragma unroll
      for (int i = 0; i < 2; ++i)
        af[i] = *(const short8*)((const char*)As + aoff[i][ks]);
#pragma unroll
      for (int n = 0; n < 4; ++n)
        bf[n] = *(const short8*)((const char*)Bs + boff[n][ks]);
#pragma unroll
      for (int i = 0; i < 2; ++i)
#pragma unroll
        for (int n = 0; n < 4; ++n)
          acc[i][n] = __builtin_amdgcn_mfma_f32_16x16x32_bf16(af[i], bf[n], acc[i][n], 0, 0, 0);
    }
  }

  if (EPI == 0) {
#pragma unroll
    for (int i = 0; i < 2; ++i) {
      int m0 = pt * 64 + mw * 32 + i * 16 + quad * 4;
#pragma unroll
      for (int n = 0; n < 4; ++n) {
        int oc = ot * 128 + nw * 64 + n * 16 + mlane;
        float bv = bias[oc];
#pragma unroll
        for (int r = 0; r < 4; ++r) {
          int p = m0 + r;
          int y = p >> 4, x = p & 15;
          float v = fmaxf(acc[i][n][r] + bv, 0.f);
          outp[(size_t)img * 82944 + (size_t)(y * 18 + x + 19) * 256 + oc] = f2bf(v);
        }
      }
    }
  } else if (EPI == 1) {
    float ls = 0.f;
#pragma unroll
    for (int i = 0; i < 2; ++i) {
      int m0 = pt * 64 + mw * 32 + i * 16 + quad * 4;
#pragma unroll
      for (int n = 0; n < 4; ++n) {
        int oc = ot * 128 + nw * 64 + n * 16 + mlane;
        float bv = bias[oc];
        float4 c4 = *(const float4*)(cfref + (size_t)img * 65536 + (size_t)oc * 256 + m0);
        float d0 = acc[i][n][0] + bv - c4.x;
        float d1 = acc[i][n][1] + bv - c4.y;
        float d2 = acc[i][n][2] + bv - c4.z;
        float d3 = acc[i][n][3] + bv - c4.w;
        ls += d0 * d0 + d1 * d1 + d2 * d2 + d3 * d3;
      }
    }
#pragma unroll
    for (int off = 32; off; off >>= 1) ls += __shfl_down(ls, off);
    __shared__ float sred[4];
    if (lane == 0) sred[wave] = ls;
    __syncthreads();
    if (t == 0) atomicAdd(lacc, sred[0] + sred[1] + sred[2] + sred[3]);
  } else {
    float mn = INFINITY, mx = -INFINITY;
#pragma unroll
    for (int i = 0; i < 2; ++i) {
      int m0 = pt * 64 + mw * 32 + i * 16 + quad * 4;
#pragma unroll
      for (int n = 0; n < 4; ++n) {
        int oc = ot * 128 + nw * 64 + n * 16 + mlane;
        float bv = bias[oc];
        float4 v;
        v.x = acc[i][n][0] + bv; v.y = acc[i][n][1] + bv;
        v.z = acc[i][n][2] + bv; v.w = acc[i][n][3] + bv;
        mn = fminf(mn, fminf(fminf(v.x, v.y), fminf(v.z, v.w)));
        mx = fmaxf(mx, fmaxf(fmaxf(v.x, v.y), fmaxf(v.z, v.w)));
        *(float4*)(outf + (size_t)img * 65536 + (size_t)oc * 256 + m0) = v;
      }
    }
#pragma unroll
    for (int off = 32; off; off >>= 1) {
      mn = fminf(mn, __shfl_down(mn, off));
      mx = fmaxf(mx, __shfl_down(mx, off));
    }
    __shared__ float smn[4], smx[4];
    if (lane == 0) { smn[wave] = mn; smx[wave] = mx; }
    __syncthreads();
    if (t == 0) {
      mn = fminf(fminf(smn[0], smn[1]), fminf(smn[2], smn[3]));
      mx = fmaxf(fmaxf(smx[0], smx[1]), fmaxf(smx[2], smx[3]));
      atomicMin(&mm[0], mapf(mn));
      atomicMax(&mm[1], mapf(mx));
    }
  }
}

// ---------------- merged: ansb [0,1024) | bmt-transpose [1024,1152) | Recp halo [1152,1184)
__global__ __launch_bounds__(256) void ansbmt_k(
    const float* __restrict__ fs, const float* __restrict__ fd,
    const int* __restrict__ smr, const float* __restrict__ vd,
    unsigned short* __restrict__ Ans, unsigned short* __restrict__ BmT,
    unsigned short* __restrict__ Recp) {
  const int bx = blockIdx.x, t = threadIdx.x;
  if (bx < 1024) {                       // Ans[b][c][j] = ns[c][j]*v_j
    int idx = bx * 256 + t;
    int ch = idx & 31, c = (idx >> 5) & 255, b = idx >> 13;
    int j0 = ch * 8;
    int si = smr[b * 256 + c];
    unsigned short h[8] = {0, 0, 0, 0, 0, 0, 0, 0};
    if (si >= 0) {
      int m = si >> 8, r = si & 255;
      const float* fp = fs + (((size_t)b * 2 + m) * 256 + r) * 256 + j0;
      const float* vp = vd + b * 256 + j0;
#pragma unroll
      for (int i = 0; i < 8; ++i) h[i] = f2bf(fp[i] * vp[i]);
    }
    uint4 u;
    u.x = h[0] | (h[1] << 16); u.y = h[2] | (h[3] << 16);
    u.z = h[4] | (h[5] << 16); u.w = h[6] | (h[7] << 16);
    *(uint4*)&Ans[(size_t)b * 65536 + c * 256 + j0] = u;
  } else if (bx < 1152) {                // BmT[b][p][j] = fd[b,m_p,j,r_p]
    __shared__ float sIn[4096];          // 8 j x 2 m x 256 r
    const int b = (bx - 1024) >> 2, bz = (bx - 1024) & 3;
    const int sp = smr[b * 256 + t];
    const int m_p = sp >> 8, r_p = sp & 255;
    for (int jg = bz * 8; jg < bz * 8 + 8; ++jg) {
      __syncthreads();
#pragma unroll
      for (int u = 0; u < 4; ++u) {
        int q = t * 4 + u;
        int rr = q >> 6, w = q & 63;
        int m = rr >> 3, i = rr & 7;
        float4 f = ((const float4*)fd)[((size_t)(b * 2 + m) * 256 + jg * 8 + i) * 64 + w];
        *(float4*)&sIn[i * 512 + m * 256 + w * 4] = f;
      }
      __syncthreads();
      unsigned short h[8] = {0, 0, 0, 0, 0, 0, 0, 0};
      if (sp >= 0) {
#pragma unroll
        for (int i = 0; i < 8; ++i) h[i] = f2bf(sIn[i * 512 + m_p * 256 + r_p]);
      }
      uint4 u;
      u.x = h[0] | (h[1] << 16); u.y = h[2] | (h[3] << 16);
      u.z = h[4] | (h[5] << 16); u.w = h[6] | (h[7] << 16);
      *(uint4*)&BmT[(size_t)b * 65536 + t * 256 + jg * 8] = u;
    }
  } else {                               // Recp halo zero (32 imgs)
    int img = bx - 1152;
    uint4* base = (uint4*)Recp + (size_t)img * 10368;
    uint4 z; z.x = z.y = z.z = z.w = 0;
    for (int it = t; it < 2176; it += 256) {
      int px = it >> 5, c = it & 31;
      int y, x;
      if (px < 18)      { y = 0;  x = px; }
      else if (px < 36) { y = 17; x = px - 18; }
      else if (px < 52) { y = px - 35; x = 0; }
      else              { y = px - 51; x = 17; }
      base[(y * 18 + x) * 32 + c] = z;
    }
  }
}

// rec^T[p][c] = sum_j BmT[p][j]*Ans[c][j] -> Recp padded NHWC bf16
// Tile 64p x 128c, BK=128, 2 kits. grid (8, 32): bx = pt*2 + ct.
__global__ __launch_bounds__(256) void recgemm_k(const unsigned short* __restrict__ BmT,
                                                 const unsigned short* __restrict__ Ans,
                                                 unsigned short* __restrict__ Recp) {
  __shared__ __align__(16) unsigned short As[8192];
  __shared__ __align__(16) unsigned short Bs[16384];
  const int t = threadIdx.x, lane = t & 63, wave = t >> 6;
  const int b = blockIdx.y, pt = blockIdx.x >> 1, ct = blockIdx.x & 1;

  int laneA[4], laneB[8];
  {
    const int rl = lane >> 4, lc = lane & 15;
#pragma unroll
    for (int j = 0; j < 4; ++j) {
      int row = (wave * 4 + j) * 4 + rl;
      laneA[j] = (pt * 64 + row) * 512 + ((lc ^ (row & 15)) * 16);
    }
#pragma unroll
    for (int j = 0; j < 8; ++j) {
      int row = (wave * 8 + j) * 4 + rl;
      laneB[j] = (ct * 128 + row) * 512 + ((lc ^ (row & 15)) * 16);
    }
  }
  const char* Ag = (const char*)BmT + (size_t)b * 131072;
  const char* Bg = (const char*)Ans + (size_t)b * 131072;

  const int mlane = lane & 15, quad = lane >> 4;
  const int mw = wave >> 1, nw = wave & 1;
  int aoff[2][4], boff[4][4];
#pragma unroll
  for (int ks = 0; ks < 4; ++ks) {
#pragma unroll
    for (int i = 0; i < 2; ++i) {
      int rowm = mw * 32 + i * 16 + mlane;
      aoff[i][ks] = rowm * 256 + (((ks * 4 + quad) ^ (rowm & 15)) * 16);
    }
#pragma unroll
    for (int n = 0; n < 4; ++n) {
      int rown = nw * 64 + n * 16 + mlane;
      boff[n][ks] = rown * 256 + (((ks * 4 + quad) ^ (rown & 15)) * 16);
    }
  }

  f32x4 acc[2][4] = {};

  for (int kit = 0; kit < 2; ++kit) {
    int g = kit << 8;
    __syncthreads();
#pragma unroll
    for (int j = 0; j < 4; ++j)
      gload_lds16(Ag + laneA[j] + g, (char*)As + (wave * 4 + j) * 1024);
#pragma unroll
    for (int j = 0; j < 8; ++j)
      gload_lds16(Bg + laneB[j] + g, (char*)Bs + (wave * 8 + j) * 1024);
    __syncthreads();
#pragma unroll
    for (int ks = 0; ks < 4; ++ks) {
      short8 af[2], bf[4];
#pragma unroll
      for (int i = 0; i < 2; ++i)
        af[i] = *(const short8*)((const char*)As + aoff[i][ks]);
#pragma unroll
      for (int n = 0; n < 4; ++n)
        bf[n] = *(const short8*)((const char*)Bs + boff[n][ks]);
#pragma unroll
      for (int i = 0; i < 2; ++i)
#pragma unroll
        for (int n = 0; n < 4; ++n)
          acc[i][n] = __builtin_amdgcn_mfma_f32_16x16x32_bf16(af[i], bf[n], acc[i][n], 0, 0, 0);
    }
  }

#pragma unroll
  for (int i = 0; i < 2; ++i) {
    int m0 = pt * 64 + mw * 32 + i * 16 + quad * 4;
#pragma unroll
    for (int n = 0; n < 4; ++n) {
      int cc = ct * 128 + nw * 64 + n * 16 + mlane;
#pragma unroll
      for (int r = 0; r < 4; ++r) {
        int p = m0 + r;
        int y = p >> 4, x = p & 15;
        Recp[(size_t)b * 82944 + (size_t)(y * 18 + x + 19) * 256 + cc] = f2bf(acc[i][n][r]);
      }
    }
  }
}

// 256->1 score conv partials, ic-split 4-way, atomicAdd into sraw (pre-zeroed)
__global__ __launch_bounds__(256) void score_conv_k(
    const float* __restrict__ rec2, const float* __restrict__ cf,
    const float* __restrict__ wval, const unsigned* __restrict__ mm,
    float* __restrict__ sraw) {
  const int b = blockIdx.x, phase = blockIdx.y, icc = blockIdx.z;
  const int t = threadIdx.x;
  const int row = t >> 4, col = t & 15;
  __shared__ float s_in[8 * 360];
  __shared__ float s_wv[72];
  for (int i = t; i < 8 * 360; i += 256) s_in[i] = 0.f;
  const float* src;
  float sc = 1.f, sh = 0.f;
  int wofs;
  if (phase == 0) {
    src = rec2 + (size_t)b * 65536;
    float mn = unmapf(mm[0]), mx = unmapf(mm[1]);
    sc = 2.f / (mx - mn);
    sh = -mn * sc - 1.f;
    wofs = 0;
  } else {
    src = cf + ((size_t)b * 2 + (phase - 1)) * 65536;
    wofs = 2304;
  }
  float acc = 0.f;
  for (int ic0 = icc * 64; ic0 < icc * 64 + 64; ic0 += 8) {
    __syncthreads();
#pragma unroll
    for (int i = 0; i < 8; ++i) {
      float v = src[(ic0 + i) * 256 + t];
      if (phase == 0) v = fmaf(v, sc, sh);
      s_in[i * 360 + (row + 1) * 20 + (col + 1)] = v;
    }
    if (t < 72) s_wv[t] = wval[wofs + ic0 * 9 + t];
    __syncthreads();
#pragma unroll
    for (int i = 0; i < 8; ++i)
#pragma unroll
      for (int ky = 0; ky < 3; ++ky)
#pragma unroll
        for (int kx = 0; kx < 3; ++kx)
          acc += s_in[i * 360 + (row + ky) * 20 + (col + kx)] * s_wv[i * 9 + ky * 3 + kx];
  }
  atomicAdd(&sraw[((size_t)b * 3 + phase) * 256 + t], acc);
}

__global__ void fuse_k(const float* __restrict__ cf, const float* __restrict__ rec2,
                       const float* __restrict__ sraw, const float* __restrict__ bval,
                       const unsigned* __restrict__ mm, const float* __restrict__ lacc,
                       float* __restrict__ outp) {
  const int idx = blockIdx.x * 256 + threadIdx.x;
  const int b = idx >> 16;
  const int rest = idx & 65535;
  const int pos = idx & 255;
  const float mn = unmapf(mm[0]), mx = unmapf(mm[1]);
  const float sc = 2.f / (mx - mn), sh = -mn * sc - 1.f;
  const float srec = sraw[(size_t)b * 768 + pos];
  const float sc0 = sraw[(size_t)b * 768 + 256 + pos];
  const float sc1 = sraw[(size_t)b * 768 + 512 + pos];
  const float bv = bval[0];
  const float z0 = fmaxf(srec + sc0 + bv, 0.f);
  const float z1 = fmaxf(srec + sc1 + bv, 0.f);
  const float s0 = 1.f / (1.f + expf(-z0));
  const float s1 = 1.f / (1.f + expf(-z1));
  const float w0 = 1.f / (1.f + expf(s1 - s0));  // softmax over 2 modalities
  const float w1 = 1.f - w0;
  const float rn = fmaf(rec2[idx], sc, sh);
  const float f0 = cf[(size_t)b * 131072 + rest];
  const float f1 = cf[(size_t)b * 131072 + 65536 + rest];
  outp[idx] = 0.2f * (w0 * f0 + w1 * f1) + 0.8f * rn;
  if (idx == 0) outp[2097152] = lacc[0] * (1.f / 4194304.f);
}

extern "C" void kernel_launch(void* const* d_in, const int* in_sizes, int n_in,
                              void* d_out, int out_size, void* d_ws, size_t ws_size,
                              hipStream_t stream) {
  const float* cf    = (const float*)d_in[0];
  const float* fs    = (const float*)d_in[1];
  const float* fv    = (const float*)d_in[2];
  const float* fd    = (const float*)d_in[3];
  const float* w_enc = (const float*)d_in[4];
  const float* b_enc = (const float*)d_in[5];
  const float* w_dec = (const float*)d_in[6];
  const float* b_dec = (const float*)d_in[7];
  const float* w_val = (const float*)d_in[8];
  const float* b_val = (const float*)d_in[9];
  float* out = (float*)d_out;
  float* wsf = (float*)d_ws;

  // ws layout (float offsets), proven-size from R2:
  //   Xp 64-img padded NHWC bf16 [0, 2654208) -- dead after enc conv
  //     Ans @0 (1048576 fl), BmT @1048576 (1048576 fl)
  //   Midp 64-img [2654208, 5308416) -- dead after loss conv
  //     Recp 32-img @2654208 (halo re-zeroed in ansbmt_k)
  unsigned short* Xp   = (unsigned short*)wsf;
  unsigned short* Ans  = (unsigned short*)wsf;
  unsigned short* BmT  = (unsigned short*)(wsf + 1048576);
  unsigned short* Midp = (unsigned short*)(wsf + 2654208);
  unsigned short* Recp = (unsigned short*)(wsf + 2654208);
  float* rec2 = wsf + 5308416;                    // 2,097,152 (NCHW f32)
  unsigned short* WrE = (unsigned short*)(wsf + 7405568);
  unsigned short* WrD = (unsigned short*)(wsf + 7700480);
  float* sraw = wsf + 7995392;                    // 24,576
  float* vd   = wsf + 8019968;                    // 8,192
  int*   smr  = (int*)(wsf + 8028160);            // 8,192
  float* lacc = wsf + 8036352;
  unsigned* mm = (unsigned*)(wsf + 8036354);

  prep_k<<<2809, 256, 0, stream>>>(cf, w_enc, w_dec, fv, Xp, WrE, WrD, smr, vd,
                                   (float4*)sraw, lacc, mm);
  convmma_k<0><<<dim3(8, 64), 256, 0, stream>>>(Xp, WrE, b_enc, nullptr, Midp, nullptr, nullptr, nullptr);
  convmma_k<1><<<dim3(8, 64), 256, 0, stream>>>(Midp, WrD, b_dec, cf, nullptr, nullptr, lacc, nullptr);
  ansbmt_k<<<1184, 256, 0, stream>>>(fs, fd, smr, vd, Ans, BmT, Recp);
  recgemm_k<<<dim3(8, 32), 256, 0, stream>>>(BmT, Ans, Recp);
  convmma_k<2><<<dim3(8, 32), 256, 0, stream>>>(Recp, WrD, b_dec, nullptr, nullptr, rec2, nullptr, mm);
  score_conv_k<<<dim3(32, 3, 4), 256, 0, stream>>>(rec2, cf, w_val, mm, sraw);
  fuse_k<<<8192, 256, 0, stream>>>(cf, rec2, sraw, b_val, mm, lacc, out);
}